// Round 8
// baseline (1588.141 us; speedup 1.0000x reference)
//
#include <hip/hip_runtime.h>

// HMM forward, B=64, T=1024, S=512, V=1024.
// Round 8: TWO BATCHES PER BLOCK, phase-interleaved (32 blocks x 512 threads).
// Both batches share the E fragments (same Bf registers). Per iteration:
//   B1 -> [quant A  || MFMA B -> wdB -> DPP max B] -> B2
//      -> [quant B  || MFMA A -> wdA -> DPP max A] -> (next B1)
// Each batch's quantize/reduce chain hides under the OTHER batch's MFMA wall
// (separate pipes). 2 barriers advance BOTH batches one step. Single-buffered
// PqA/PqB/redmA/redmB: every write->read pair is barrier-separated.
// Per-batch numerics identical to round 7 (exp-domain ring, exact global max):
//   wd'_j = exp(e_j) * idot_j ; q_j = round(lrf_j * wd_j / W) ; S' = S+lnW+C.

constexpr int Bn = 64, Tn = 1024, Sn = 512;
#define L2E 1.44269504f

typedef int v4i __attribute__((ext_vector_type(4)));

#if __has_builtin(__builtin_amdgcn_update_dpp)
template <int CTRL>
__device__ __forceinline__ float dpp_fmax(float x) {
    int s = __builtin_bit_cast(int, x);
    int d = __builtin_amdgcn_update_dpp(s, s, CTRL, 0xf, 0xf, false);
    return fmaxf(x, __builtin_bit_cast(float, d));
}
__device__ __forceinline__ float wave_max64(float x) {
    x = dpp_fmax<0x121>(x);   // row_ror:1
    x = dpp_fmax<0x122>(x);   // row_ror:2
    x = dpp_fmax<0x124>(x);   // row_ror:4
    x = dpp_fmax<0x128>(x);   // row_ror:8
    x = dpp_fmax<0x142>(x);   // row_bcast:15
    x = dpp_fmax<0x143>(x);   // row_bcast:31
    return __builtin_bit_cast(float,
        __builtin_amdgcn_readlane(__builtin_bit_cast(int, x), 63));
}
#else
__device__ __forceinline__ float wave_max64(float x) {
    #pragma unroll
    for (int off = 32; off; off >>= 1) x = fmaxf(x, __shfl_xor(x, off, 64));
    return x;
}
#endif

__device__ __forceinline__ float tree8(const float* p) {
    float4 r0 = *(const float4*)p;
    float4 r1 = *(const float4*)(p + 4);
    return fmaxf(fmaxf(fmaxf(r0.x, r0.y), fmaxf(r0.z, r0.w)),
                 fmaxf(fmaxf(r1.x, r1.y), fmaxf(r1.z, r1.w)));
}

// P(1x512) x Eq(512x512) via 4 n-tiles x 8 k-chunks, chained accumulators.
__device__ __forceinline__ float mfma_dot(const unsigned char* Pq_,
                                          const v4i (&Bf)[4][8],
                                          int q, int lane) {
    const unsigned char* Pb = Pq_ + q * 16;
    v4i Af[8];
    #pragma unroll
    for (int kap = 0; kap < 8; ++kap)
        Af[kap] = *(const v4i*)(Pb + kap * 64);
    v4i acc[4];
    #pragma unroll
    for (int tau = 0; tau < 4; ++tau) {
        v4i z = {0, 0, 0, 0};
        #pragma unroll
        for (int kap = 0; kap < 8; ++kap)
            z = __builtin_amdgcn_mfma_i32_16x16x64_i8(Af[kap], Bf[tau][kap],
                                                      z, 0, 0, 0);
        acc[tau] = z;
    }
    int idot = (lane < 16) ? acc[0].x
             : (lane < 32) ? acc[1].x
             : (lane < 48) ? acc[2].x
                           : acc[3].x;
    return (float)idot;
}

// Eq value for (row i, col c) -> B-fragment byte address:
// frag = (c>>4)*8 + (i>>6); lane = ((i>>4)&3)*16 + (c&15); byte = i&15
__device__ __forceinline__ int bfrag_addr(int i, int c) {
    return ((((c >> 4) * 8 + (i >> 6)) * 64) + ((i >> 4) & 3) * 16 + (c & 15)) * 16
           + (i & 15);
}

// One block per row i: rowmax + quantize row to u8, scatter into B-frag layout.
__global__ __launch_bounds__(256) void prep_rows(
    const float* __restrict__ trans, unsigned char* __restrict__ EqB,
    float* __restrict__ rowmax)
{
    const int i = blockIdx.x;
    const int j = threadIdx.x;
    const int lane = j & 63, wv = j >> 6;
    float t0 = trans[i * Sn + j];
    float t1 = trans[i * Sn + j + 256];
    float m = fmaxf(t0, t1);
    #pragma unroll
    for (int off = 32; off; off >>= 1) m = fmaxf(m, __shfl_xor(m, off, 64));
    __shared__ float rm[4];
    if (lane == 0) rm[wv] = m;
    __syncthreads();
    m = fmaxf(fmaxf(rm[0], rm[1]), fmaxf(rm[2], rm[3]));
    if (j == 0) rowmax[i] = m;
    int q0 = __float2int_rn(127.f * __expf(t0 - m));
    int q1 = __float2int_rn(127.f * __expf(t1 - m));
    EqB[bfrag_addr(i, j)] = (unsigned char)q0;
    EqB[bfrag_addr(i, j + 256)] = (unsigned char)q1;
}

// lr[i] = log2(127 * exp(rowmax_i - RM)); C = RM - 2*ln(127)
__global__ __launch_bounds__(512) void prep_scale(
    const float* __restrict__ rowmax, float* __restrict__ lr,
    float* __restrict__ Cp)
{
    const int i = threadIdx.x;
    const int lane = i & 63, wv = i >> 6;
    float m = rowmax[i];
    float rm = m;
    #pragma unroll
    for (int off = 32; off; off >>= 1) rm = fmaxf(rm, __shfl_xor(rm, off, 64));
    __shared__ float red[8];
    if (lane == 0) red[wv] = rm;
    __syncthreads();
    float RM = red[0];
    #pragma unroll
    for (int w = 1; w < 8; ++w) RM = fmaxf(RM, red[w]);
    lr[i] = (m - RM) * L2E + 6.98868469f;           // log2(127)
    if (i == 0) *Cp = RM - 9.68837417f;             // 2*ln(127)
}

__global__ __launch_bounds__(512, 2) void hmm_fwd2(
    const int* __restrict__ obs,          // [B, T]
    const float* __restrict__ emis,       // [V, S]
    const float* __restrict__ prior,      // [S]
    const v4i* __restrict__ EqB4,         // B-fragments, 16B per (frag,lane)
    const float* __restrict__ lr,         // [S]
    const float* __restrict__ Cp,         // scalar
    float* __restrict__ out)              // [B]
{
    const int bA = blockIdx.x * 2, bB = bA + 1;
    const int tid = threadIdx.x;          // state j owned by this thread
    const int lane = tid & 63, wv = tid >> 6;
    const int q = lane >> 4;

    __shared__ int obsA_s[Tn + 1], obsB_s[Tn + 1];
    __shared__ __align__(16) unsigned char PqA[Sn], PqB[Sn];
    __shared__ __align__(16) float redmA[8], redmB[8];
    __shared__ float reds[16];

    int a0 = obs[bA * Tn + tid], a1 = obs[bA * Tn + 512 + tid];
    int b0 = obs[bB * Tn + tid], b1 = obs[bB * Tn + 512 + tid];
    obsA_s[tid] = a0; obsA_s[tid + 512] = a1;
    obsB_s[tid] = b0; obsB_s[tid + 512] = b1;
    if (tid == 511) { obsA_s[Tn] = a1; obsB_s[Tn] = b1; }   // branch-free pad

    // Shared E fragments: cols wv*64+tau*16+(lane&15), rows kap*64+subchunks
    v4i Bf[4][8];
    #pragma unroll
    for (int tau = 0; tau < 4; ++tau)
        #pragma unroll
        for (int kap = 0; kap < 8; ++kap)
            Bf[tau][kap] = EqB4[((wv * 4 + tau) * 8 + kap) * 64 + lane];

    const float lrf = exp2f(lr[tid]);     // 127 * exp(rowmax_j - RM), <= 127
    const float C = *Cp;

    __syncthreads();   // obs_s ready

    float wdA = __expf(emis[obsA_s[0] * Sn + tid] + prior[tid]);
    float wdB = __expf(emis[obsB_s[0] * Sn + tid] + prior[tid]);
    float lwA = lrf * wdA, lwB = lrf * wdB;
    float SA = 0.f, SB = 0.f;
    float eNA = emis[obsA_s[1] * Sn + tid];
    float eNB = emis[obsB_s[1] * Sn + tid];

    // ---- prologue: publish P_B (transition 0->1), stage redmA
    float mwB = wave_max64(wdB);
    if (lane == 0) redmB[wv] = mwB;
    __syncthreads();
    {
        float WB = tree8(redmB);
        int giB = __float2int_rn(lwB * __builtin_amdgcn_rcpf(WB));
        PqB[tid] = (unsigned char)giB;
        SB += __logf(WB) + C;
    }
    float mwA = wave_max64(wdA);
    if (lane == 0) redmA[wv] = mwA;

    for (int t = 1; t < Tn; ++t) {
        __syncthreads();                       // B1: redmA, PqB visible
        float weCA = __expf(eNA);              // off-path (TRANS)
        float weCB = __expf(eNB);

        // ---- quant A (transition t-1 -> t)   [hides under MFMA B]
        {
            float WA = tree8(redmA);
            int giA = __float2int_rn(lwA * __builtin_amdgcn_rcpf(WA));
            PqA[tid] = (unsigned char)giA;
            SA += __logf(WA) + C;
        }
        eNA = emis[obsA_s[t + 1] * Sn + tid];  // prefetch step t+1

        // ---- MFMA B (step t)
        float dfB = mfma_dot(PqB, Bf, q, lane);
        wdB = weCB * dfB;
        lwB = lrf * wdB;
        float mB = wave_max64(wdB);
        if (lane == 0) redmB[wv] = mB;

        __syncthreads();                       // B2: PqA, redmB visible
        eNB = emis[obsB_s[t + 1] * Sn + tid];  // prefetch step t+1

        // ---- quant B (transition t -> t+1)   [hides under MFMA A]
        if (t < Tn - 1) {
            float WB = tree8(redmB);
            int giB = __float2int_rn(lwB * __builtin_amdgcn_rcpf(WB));
            PqB[tid] = (unsigned char)giB;
            SB += __logf(WB) + C;
        }

        // ---- MFMA A (step t)
        float dfA = mfma_dot(PqA, Bf, q, lane);
        wdA = weCA * dfA;
        lwA = lrf * wdA;
        float mA = wave_max64(wdA);
        if (lane == 0) redmA[wv] = mA;
    }

    // ---- epilogue: out[b] = S + ln(sum_j wd_j) for both batches
    __syncthreads();                           // redmA/redmB final values visible
    float WfA = tree8(redmA);
    float WfB = tree8(redmB);
    float sA = wdA * __builtin_amdgcn_rcpf(WfA);
    float sB = wdB * __builtin_amdgcn_rcpf(WfB);
    #pragma unroll
    for (int off = 32; off; off >>= 1) {
        sA += __shfl_xor(sA, off, 64);
        sB += __shfl_xor(sB, off, 64);
    }
    if (lane == 0) { reds[wv] = sA; reds[8 + wv] = sB; }
    __syncthreads();
    if (tid == 0) {
        float tot = 0.f;
        #pragma unroll
        for (int w = 0; w < 8; ++w) tot += reds[w];
        out[bA] = SA + __logf(WfA) + __logf(tot);
    }
    if (tid == 64) {
        float tot = 0.f;
        #pragma unroll
        for (int w = 0; w < 8; ++w) tot += reds[8 + w];
        out[bB] = SB + __logf(WfB) + __logf(tot);
    }
}

extern "C" void kernel_launch(void* const* d_in, const int* in_sizes, int n_in,
                              void* d_out, int out_size, void* d_ws, size_t ws_size,
                              hipStream_t stream) {
    const int*   obs   = (const int*)d_in[0];
    const float* emis  = (const float*)d_in[1];
    const float* trans = (const float*)d_in[2];
    const float* prior = (const float*)d_in[3];
    float* out = (float*)d_out;

    unsigned char* EqB = (unsigned char*)d_ws;                // 256 KB
    float* rowmax = (float*)(EqB + Sn * Sn);                  // 2 KB
    float* lr     = rowmax + Sn;                              // 2 KB
    float* Cp     = lr + Sn;                                  // 4 B

    prep_rows<<<Sn, 256, 0, stream>>>(trans, EqB, rowmax);
    prep_scale<<<1, Sn, 0, stream>>>(rowmax, lr, Cp);
    hmm_fwd2<<<Bn / 2, Sn, 0, stream>>>(obs, emis, prior,
                                        (const v4i*)EqB, lr, Cp, out);
}

// Round 9
// 902.338 us; speedup vs baseline: 1.7600x; 1.7600x over previous
//
#include <hip/hip_runtime.h>

// HMM forward, B=64, T=1024, S=512, V=1024.
// Round 9: polish of the proven round-7 kernel (911 us dispatch).
// Structure: one block per batch; E = exp(trans) u8 B-fragments in 128 AGPRs;
// exp-domain ring (no log/exp on the critical path); exact global max via
// DPP + one LDS round-trip; 2 barriers/step; 256 x mfma_i32_16x16x64_i8.
// Polish vs round 7:
//  - single-buffered Pq/redm (read -> next write always barrier-separated)
//  - wave max written from lane 63 (DPP result lane) -- no v_readlane on path
//  - obs/emis prefetch hoisted (obs read pre-bar1, emis load right after bar2)
//  - prep_scale fused into hmm_fwd prologue (one fewer launch, no lr/Cp RT)

constexpr int Bn = 64, Tn = 1024, Sn = 512;
#define L2E 1.44269504f

typedef int v4i __attribute__((ext_vector_type(4)));

#if __has_builtin(__builtin_amdgcn_update_dpp)
template <int CTRL>
__device__ __forceinline__ float dpp_fmax(float x) {
    int s = __builtin_bit_cast(int, x);
    int d = __builtin_amdgcn_update_dpp(s, s, CTRL, 0xf, 0xf, false);
    return fmaxf(x, __builtin_bit_cast(float, d));
}
// Full-wave max; result valid in lane 63 (no readlane broadcast).
__device__ __forceinline__ float wave_max64_l63(float x) {
    x = dpp_fmax<0x121>(x);   // row_ror:1
    x = dpp_fmax<0x122>(x);   // row_ror:2
    x = dpp_fmax<0x124>(x);   // row_ror:4
    x = dpp_fmax<0x128>(x);   // row_ror:8
    x = dpp_fmax<0x142>(x);   // row_bcast:15
    x = dpp_fmax<0x143>(x);   // row_bcast:31
    return x;
}
__device__ __forceinline__ float wave_max64(float x) {
    return __builtin_bit_cast(float,
        __builtin_amdgcn_readlane(
            __builtin_bit_cast(int, wave_max64_l63(x)), 63));
}
#else
__device__ __forceinline__ float wave_max64(float x) {
    #pragma unroll
    for (int off = 32; off; off >>= 1) x = fmaxf(x, __shfl_xor(x, off, 64));
    return x;
}
__device__ __forceinline__ float wave_max64_l63(float x) { return wave_max64(x); }
#endif

// Eq value for (row i, col c) -> B-fragment byte address:
// frag = (c>>4)*8 + (i>>6); lane = ((i>>4)&3)*16 + (c&15); byte = i&15
__device__ __forceinline__ int bfrag_addr(int i, int c) {
    return ((((c >> 4) * 8 + (i >> 6)) * 64) + ((i >> 4) & 3) * 16 + (c & 15)) * 16
           + (i & 15);
}

// One block per row i: rowmax + quantize row to u8, scatter into B-frag layout.
__global__ __launch_bounds__(256) void prep_rows(
    const float* __restrict__ trans, unsigned char* __restrict__ EqB,
    float* __restrict__ rowmax)
{
    const int i = blockIdx.x;
    const int j = threadIdx.x;
    const int lane = j & 63, wv = j >> 6;
    float t0 = trans[i * Sn + j];
    float t1 = trans[i * Sn + j + 256];
    float m = fmaxf(t0, t1);
    #pragma unroll
    for (int off = 32; off; off >>= 1) m = fmaxf(m, __shfl_xor(m, off, 64));
    __shared__ float rm[4];
    if (lane == 0) rm[wv] = m;
    __syncthreads();
    m = fmaxf(fmaxf(rm[0], rm[1]), fmaxf(rm[2], rm[3]));
    if (j == 0) rowmax[i] = m;
    int q0 = __float2int_rn(127.f * __expf(t0 - m));
    int q1 = __float2int_rn(127.f * __expf(t1 - m));
    EqB[bfrag_addr(i, j)] = (unsigned char)q0;
    EqB[bfrag_addr(i, j + 256)] = (unsigned char)q1;
}

__global__ __launch_bounds__(512, 2) void hmm_fwd(
    const int* __restrict__ obs,          // [B, T]
    const float* __restrict__ emis,       // [V, S]
    const float* __restrict__ prior,      // [S]
    const v4i* __restrict__ EqB4,         // B-fragments, 16B per (frag,lane)
    const float* __restrict__ rowmax,     // [S]
    float* __restrict__ out)              // [B]
{
    const int b = blockIdx.x;
    const int tid = threadIdx.x;          // state j owned by this thread
    const int lane = tid & 63, wv = tid >> 6;
    const int q = lane >> 4;

    __shared__ int obs_s[Tn + 1];
    __shared__ __align__(16) unsigned char Pq[Sn];
    __shared__ __align__(16) float redm[8];
    __shared__ float reds[8];

    int o0 = obs[b * Tn + tid];
    int o1 = obs[b * Tn + 512 + tid];
    obs_s[tid] = o0;
    obs_s[tid + 512] = o1;
    if (tid == 511) obs_s[Tn] = o1;       // pad: branch-free prefetch

    // B-fragments: Bf[tau][kap] = E rows kap*64+(16k-subchunks), cols wv*64+tau*16+(lane&15)
    v4i Bf[4][8];
    #pragma unroll
    for (int tau = 0; tau < 4; ++tau)
        #pragma unroll
        for (int kap = 0; kap < 8; ++kap)
            Bf[tau][kap] = EqB4[((wv * 4 + tau) * 8 + kap) * 64 + lane];

    // ---- fused prep_scale: RM = max_i rowmax[i]; lrf_j = 127*exp(rowmax_j-RM)
    float rmj = rowmax[tid];
    {
        float r = wave_max64(rmj);
        if (lane == 0) redm[wv] = r;
    }
    __syncthreads();   // covers obs_s staging AND redm
    float RM;
    {
        float4 r0 = *(const float4*)&redm[0];
        float4 r1 = *(const float4*)&redm[4];
        RM = fmaxf(fmaxf(fmaxf(r0.x, r0.y), fmaxf(r0.z, r0.w)),
                   fmaxf(fmaxf(r1.x, r1.y), fmaxf(r1.z, r1.w)));
    }
    const float lrf = exp2f((rmj - RM) * L2E + 6.98868469f);  // log2(127)
    const float C = RM - 9.68837417f;                          // 2*ln(127)

    // alpha_0 in exp form: a_j = S + ln(wd_j), S = 0
    float wd = __expf(emis[obs_s[0] * Sn + tid] + prior[tid]);
    float lw = lrf * wd;
    float S = 0.f;
    float eC = emis[obs_s[1] * Sn + tid];   // raw emission for step 1

    for (int t = 1; t < Tn; ++t) {
        // ---- exact block max of wd: DPP in-wave (result in lane 63)
        float mx = wave_max64_l63(wd);
        if (lane == 63) redm[wv] = mx;
        int oN = obs_s[t + 1];                    // early LDS read (hidden)
        __syncthreads();                          // barrier 1
        float4 r0 = *(const float4*)&redm[0];
        float4 r1 = *(const float4*)&redm[4];
        float W = fmaxf(fmaxf(fmaxf(r0.x, r0.y), fmaxf(r0.z, r0.w)),
                        fmaxf(fmaxf(r1.x, r1.y), fmaxf(r1.z, r1.w)));

        float weC = __expf(eC);                   // TRANS, off-path

        // ---- quantize: q = round(lrf * wd / W)
        float rw = __builtin_amdgcn_rcpf(W);
        int gi = __float2int_rn(lw * rw);
        Pq[tid] = (unsigned char)gi;
        __syncthreads();                          // barrier 2

        eC = emis[oN * Sn + tid];                 // prefetch t+1 (hidden by MFMA)
        S += __logf(W) + C;                       // off-path scalar accumulate

        // ---- A-fragments: quad-broadcast reads of P (all 16 A-rows identical)
        const unsigned char* Pbase = Pq + q * 16;
        v4i Af[8];
        #pragma unroll
        for (int kap = 0; kap < 8; ++kap)
            Af[kap] = *(const v4i*)(Pbase + kap * 64);

        // ---- 4 n-tiles x 8 k-chunks of mfma_i32_16x16x64_i8
        v4i acc[4];
        #pragma unroll
        for (int tau = 0; tau < 4; ++tau) {
            v4i z = {0, 0, 0, 0};
            #pragma unroll
            for (int kap = 0; kap < 8; ++kap)
                z = __builtin_amdgcn_mfma_i32_16x16x64_i8(Af[kap], Bf[tau][kap],
                                                          z, 0, 0, 0);
            acc[tau] = z;
        }

        // ---- every C row equals the result: select tau = lane>>4 in-register
        int idot = (lane < 16) ? acc[0].x
                 : (lane < 32) ? acc[1].x
                 : (lane < 48) ? acc[2].x
                               : acc[3].x;

        // ---- alpha update in exp form
        wd = weC * (float)idot;
        lw = lrf * wd;
    }

    // ---- out[b] = S + ln(sum_j wd_j)  via max-normalized sum
    float mw = wave_max64(wd);
    if (lane == 0) redm[wv] = mw;
    __syncthreads();
    float Wf = mw;
    #pragma unroll
    for (int w = 0; w < 8; ++w) Wf = fmaxf(Wf, redm[w]);

    float s = wd * __builtin_amdgcn_rcpf(Wf);
    #pragma unroll
    for (int off = 32; off; off >>= 1) s += __shfl_xor(s, off, 64);
    if (lane == 0) reds[wv] = s;
    __syncthreads();
    if (tid == 0) {
        float tot = 0.f;
        #pragma unroll
        for (int w = 0; w < 8; ++w) tot += reds[w];
        out[b] = S + __logf(Wf) + __logf(tot);
    }
}

extern "C" void kernel_launch(void* const* d_in, const int* in_sizes, int n_in,
                              void* d_out, int out_size, void* d_ws, size_t ws_size,
                              hipStream_t stream) {
    const int*   obs   = (const int*)d_in[0];
    const float* emis  = (const float*)d_in[1];
    const float* trans = (const float*)d_in[2];
    const float* prior = (const float*)d_in[3];
    float* out = (float*)d_out;

    unsigned char* EqB = (unsigned char*)d_ws;                // 256 KB
    float* rowmax = (float*)(EqB + Sn * Sn);                  // 2 KB

    prep_rows<<<Sn, 256, 0, stream>>>(trans, EqB, rowmax);
    hmm_fwd<<<Bn, Sn, 0, stream>>>(obs, emis, prior,
                                   (const v4i*)EqB, rowmax, out);
}